// Round 3
// baseline (301.976 us; speedup 1.0000x reference)
//
#include <hip/hip_runtime.h>
#include <stdint.h>

// YOLO loss: S=7, B=2, C=80. preds cell = 90 f32, target cell = 85 f32.
// Output: 4 f32 scalars (coords, obj, noobj, classes), summed over 401408 cells.
//
// v4: global_load_lds double-buffered pipeline.
//   Evidence (r2 post-mortem): v3's VGPR_Count=56 < 48-VGPR load payload ->
//   compiler serialized the 12-float4 burst into register-recycling groups
//   with exposed ~900cy latency chains; all pipes idle at 2.4 TB/s effective.
//   v4 stages both slabs direct to LDS (zero payload regs), 2-phase counted
//   pipeline: STAGE(next)=6 DMA/wave -> s_waitcnt vmcnt(6) -> raw s_barrier
//   (NOT __syncthreads: that drains vmcnt(0)) -> compute(cur) -> barrier.

#define NPRED 90
#define NTGT  85
#define NCLS  80
#define CHUNK 32
#define TPB   256
#define NBLK  768  // 3 blocks/CU (LDS 2x22.4KB) * 256 CUs

#define NT4 (CHUNK * NTGT / 4)   // 680 float4 per targ slab
#define NP4 (CHUNK * NPRED / 4)  // 720 float4 per preds slab

#define WAITVM6() asm volatile("s_waitcnt vmcnt(6)" ::: "memory")
#define WAITVM0() asm volatile("s_waitcnt vmcnt(0)" ::: "memory")
#define BARRIER() do { __builtin_amdgcn_sched_barrier(0); \
                       __builtin_amdgcn_s_barrier();      \
                       __builtin_amdgcn_sched_barrier(0); } while (0)

__device__ __forceinline__ void load_lds16(const float4* g, float4* l) {
    // per-lane global src; LDS dest = wave-uniform base + lane*16
    __builtin_amdgcn_global_load_lds(
        (const __attribute__((address_space(1))) void*)g,
        (__attribute__((address_space(3))) void*)l,
        16, 0, 0);
}

__device__ __forceinline__ float sgnf(float x) {
    // matches jnp.sign: sign(0) == 0
    return (x > 0.0f) ? 1.0f : ((x < 0.0f) ? -1.0f : 0.0f);
}

__device__ __forceinline__ float iou_vs_target(
    float acx, float acy, float aw, float ah,
    float bx1, float by1, float bx2, float by2, float area_b)
{
    float ax1 = acx - aw * 0.5f, ay1 = acy - ah * 0.5f;
    float ax2 = acx + aw * 0.5f, ay2 = acy + ah * 0.5f;
    float iw = fmaxf(fminf(ax2, bx2) - fmaxf(ax1, bx1), 0.0f);
    float ih = fmaxf(fminf(ay2, by2) - fmaxf(ay1, by1), 0.0f);
    float inter = iw * ih;
    float area_a = (ax2 - ax1) * (ay2 - ay1);
    return inter / (area_a + area_b - inter);
}

// classes-loss contribution of one element (box fields j>=80 skipped entirely;
// box phase reads the preds slab from LDS directly)
__device__ __forceinline__ void pe(float v, int cl, int j, float obj,
                                   const float* __restrict__ tl, float& clsl)
{
    if (j < NCLS) {
        float d = fmaf(v, obj, -tl[cl * NTGT + j]);
        clsl = fmaf(d, d, clsl);
    }
}

__device__ __forceinline__ void proc_quad(float4 v, int q,
    const float* __restrict__ tl, float& clsl)
{
    int f  = 4 * q;            // flat element index within slab, even
    int cl = f / NPRED;        // magic-mul
    int j  = f - cl * NPRED;   // even, <= 88
    if (j != 88) {
        float obj = tl[cl * NTGT + NCLS];
        pe(v.x, cl, j,     obj, tl, clsl);
        pe(v.y, cl, j + 1, obj, tl, clsl);
        pe(v.z, cl, j + 2, obj, tl, clsl);
        pe(v.w, cl, j + 3, obj, tl, clsl);
    } else {
        // x,y are box fields of cl; z,w wrap to classes 0,1 of cl+1
        float obj2 = tl[(cl + 1) * NTGT + NCLS];
        pe(v.z, cl + 1, 0, obj2, tl, clsl);
        pe(v.w, cl + 1, 1, obj2, tl, clsl);
    }
}

// stage one 32-cell chunk into LDS buffers: exactly 6 global_load_lds per wave.
// waves 0,1 -> targ slab (680 f4), waves 2,3 -> preds slab (720 f4).
// tail instrs clamp base so the last 1KB block re-covers earlier slots
// (redundant identical writes, benign).
__device__ __forceinline__ void stage_chunk(
    const float4* __restrict__ tg, const float4* __restrict__ pg,
    float4* tb, float4* pb, int wave, int lane)
{
    if (wave < 2) {
        #pragma unroll
        for (int s = 0; s < 6; ++s) {
            int base = (wave + 2 * s) * 64;
            if (base > NT4 - 64) base = NT4 - 64;  // 616
            load_lds16(tg + base + lane, tb + base);
        }
    } else {
        #pragma unroll
        for (int s = 0; s < 6; ++s) {
            int base = ((wave - 2) + 2 * s) * 64;
            if (base > NP4 - 64) base = NP4 - 64;  // 656
            load_lds16(pg + base + lane, pb + base);
        }
    }
}

__global__ __launch_bounds__(TPB) void yolo_loss_kernel(
    const float* __restrict__ preds, const float* __restrict__ targ,
    float* __restrict__ part, float* __restrict__ out,
    int n_cells, int mode)
{
    __shared__ float4 tbuf[2][NT4];  // 2 x 10880 B
    __shared__ float4 pbuf[2][NP4];  // 2 x 11520 B
    __shared__ float red[4][4];

    float coords = 0.0f, objl = 0.0f, noobjl = 0.0f, clsl = 0.0f;

    const int tid  = threadIdx.x;
    const int wave = tid >> 6;
    const int lane = tid & 63;
    const int n_chunks = n_cells / CHUNK;

    // contiguous chunk range per block (L2/L3 locality)
    const int start = (int)(((long long)blockIdx.x       * n_chunks) / gridDim.x);
    const int end   = (int)(((long long)(blockIdx.x + 1) * n_chunks) / gridDim.x);

    if (start < end) {
        int cur = 0;
        stage_chunk((const float4*)(targ  + (size_t)start * (CHUNK * NTGT)),
                    (const float4*)(preds + (size_t)start * (CHUNK * NPRED)),
                    tbuf[0], pbuf[0], wave, lane);

        for (int ch = start; ch < end; ++ch) {
            if (ch + 1 < end) {
                stage_chunk((const float4*)(targ  + (size_t)(ch + 1) * (CHUNK * NTGT)),
                            (const float4*)(preds + (size_t)(ch + 1) * (CHUNK * NPRED)),
                            tbuf[cur ^ 1], pbuf[cur ^ 1], wave, lane);
                WAITVM6();   // cur's 6 DMAs done; next's 6 stay in flight
            } else {
                WAITVM0();
            }
            BARRIER();       // all waves' staging of cur landed

            const float* tl = (const float*)&tbuf[cur][0];
            const float* pl = (const float*)&pbuf[cur][0];

            // ---- classes loss: 720 preds-quads striped over 256 threads ----
            proc_quad(pbuf[cur][tid],       tid,       tl, clsl);
            proc_quad(pbuf[cur][tid + 256], tid + 256, tl, clsl);
            if (tid < NP4 - 512) // 208
                proc_quad(pbuf[cur][tid + 512], tid + 512, tl, clsl);

            // ---- box losses: lane c handles cell c ----
            if (tid < CHUNK) {
                const float* pb = pl + tid * NPRED + NCLS;  // p[80..89]
                const float* tc = tl + tid * NTGT + NCLS;   // t[80..84]
                float obj = tc[0];
                float tcx = tc[1], tcy = tc[2], tw = tc[3], th = tc[4];
                float bx1 = tcx - tw * 0.5f, by1 = tcy - th * 0.5f;
                float bx2 = tcx + tw * 0.5f, by2 = tcy + th * 0.5f;
                float area_b = (bx2 - bx1) * (by2 - by1);

                // box1 = p[86..89], box2 = p[81..84]
                float iou1 = iou_vs_target(pb[6], pb[7], pb[8], pb[9],
                                           bx1, by1, bx2, by2, area_b);
                float iou2 = iou_vs_target(pb[1], pb[2], pb[3], pb[4],
                                           bx1, by1, bx2, by2, area_b);
                bool use2 = iou2 > iou1;  // argmax: tie -> box1

                float pcx = obj * (use2 ? pb[1] : pb[6]);
                float pw  = obj * (use2 ? pb[3] : pb[8]);
                float ph  = obj * (use2 ? pb[4] : pb[9]);

                // center loss uses ONLY cx (ref's [..., :-3] on a 4-vector)
                float dc = pcx - tcx;
                float dw = sgnf(pw) * sqrtf(fabsf(pw) + 1e-6f) - sqrtf(tw);
                float dh = sgnf(ph) * sqrtf(fabsf(ph) + 1e-6f) - sqrtf(th);
                coords = fmaf(dc, dc, coords);
                coords = fmaf(dw, dw, coords);
                coords = fmaf(dh, dh, coords);

                float obj_pred = use2 ? pb[0] : pb[5];  // p[80] : p[85]
                float e1 = fmaf(obj, obj_pred, -obj);
                objl = fmaf(e1, e1, objl);
                float e2 = fmaf(1.0f - obj, obj_pred, -obj);
                noobjl = fmaf(e2, e2, noobjl);
            }

            BARRIER();   // WAR: everyone done reading cur before it's restaged
            cur ^= 1;
        }
    }

    // ---- remainder cells (none when n_cells % 32 == 0): scalar fallback ----
    for (int cell = n_chunks * CHUNK + (int)(blockIdx.x * TPB + tid);
         cell < n_cells; cell += gridDim.x * TPB) {
        const float* p = preds + (size_t)cell * NPRED;
        const float* t = targ  + (size_t)cell * NTGT;
        float obj = t[NCLS];
        float cls = 0.0f;
        for (int k = 0; k < NCLS; ++k) {
            float d = fmaf(p[k], obj, -t[k]);
            cls = fmaf(d, d, cls);
        }
        clsl += cls;
        float tcx = t[81], tcy = t[82], tw = t[83], th = t[84];
        float bx1 = tcx - tw * 0.5f, by1 = tcy - th * 0.5f;
        float bx2 = tcx + tw * 0.5f, by2 = tcy + th * 0.5f;
        float area_b = (bx2 - bx1) * (by2 - by1);
        float iou1 = iou_vs_target(p[86], p[87], p[88], p[89],
                                   bx1, by1, bx2, by2, area_b);
        float iou2 = iou_vs_target(p[81], p[82], p[83], p[84],
                                   bx1, by1, bx2, by2, area_b);
        bool use2 = iou2 > iou1;
        float pcx = obj * (use2 ? p[81] : p[86]);
        float pw  = obj * (use2 ? p[83] : p[88]);
        float ph  = obj * (use2 ? p[84] : p[89]);
        float dc = pcx - tcx;
        float dw = sgnf(pw) * sqrtf(fabsf(pw) + 1e-6f) - sqrtf(tw);
        float dh = sgnf(ph) * sqrtf(fabsf(ph) + 1e-6f) - sqrtf(th);
        coords = fmaf(dc, dc, coords);
        coords = fmaf(dw, dw, coords);
        coords = fmaf(dh, dh, coords);
        float obj_pred = use2 ? p[80] : p[85];
        float e1 = fmaf(obj, obj_pred, -obj);
        objl = fmaf(e1, e1, objl);
        float e2 = fmaf(1.0f - obj, obj_pred, -obj);
        noobjl = fmaf(e2, e2, noobjl);
    }

    // ---- wave reduce (64 lanes) ----
    #pragma unroll
    for (int off = 32; off > 0; off >>= 1) {
        coords += __shfl_down(coords, off);
        objl   += __shfl_down(objl, off);
        noobjl += __shfl_down(noobjl, off);
        clsl   += __shfl_down(clsl, off);
    }

    __syncthreads();   // pipeline fully drained; safe full barrier
    if (lane == 0) {
        red[0][wave] = coords;
        red[1][wave] = objl;
        red[2][wave] = noobjl;
        red[3][wave] = clsl;
    }
    __syncthreads();
    if (tid == 0) {
        float c = red[0][0] + red[0][1] + red[0][2] + red[0][3];
        float o = red[1][0] + red[1][1] + red[1][2] + red[1][3];
        float n = red[2][0] + red[2][1] + red[2][2] + red[2][3];
        float k = red[3][0] + red[3][1] + red[3][2] + red[3][3];
        if (mode == 0) {
            // component-major partials: no contention, plain stores
            int nb = gridDim.x;
            part[0 * nb + blockIdx.x] = c;
            part[1 * nb + blockIdx.x] = o;
            part[2 * nb + blockIdx.x] = n;
            part[3 * nb + blockIdx.x] = k;
        } else {
            atomicAdd(&out[0], 5.0f * c);
            atomicAdd(&out[1], o);
            atomicAdd(&out[2], 0.5f * n);
            atomicAdd(&out[3], k);
        }
    }
}

// one block, 4 waves: wave w reduces component w over nblk partials
__global__ __launch_bounds__(256) void yolo_reduce_kernel(
    const float* __restrict__ part, float* __restrict__ out, int nblk)
{
    int w = threadIdx.x >> 6;
    int lane = threadIdx.x & 63;
    float s = 0.0f;
    for (int i = lane; i < nblk; i += 64) s += part[w * nblk + i];
    #pragma unroll
    for (int off = 32; off > 0; off >>= 1) s += __shfl_down(s, off);
    if (lane == 0) {
        float scale = (w == 0) ? 5.0f : (w == 2) ? 0.5f : 1.0f;
        out[w] = s * scale;  // plain store overwrites poison
    }
}

extern "C" void kernel_launch(void* const* d_in, const int* in_sizes, int n_in,
                              void* d_out, int out_size, void* d_ws, size_t ws_size,
                              hipStream_t stream) {
    const float* preds = (const float*)d_in[0];
    const float* targ  = (const float*)d_in[1];
    float* out = (float*)d_out;

    int n_cells = in_sizes[0] / NPRED;  // 8192*7*7 = 401408

    bool use_ws = ws_size >= (size_t)(4 * NBLK) * sizeof(float);

    if (use_ws) {
        float* part = (float*)d_ws;
        hipLaunchKernelGGL(yolo_loss_kernel, dim3(NBLK), dim3(TPB), 0, stream,
                           preds, targ, part, out, n_cells, 0);
        hipLaunchKernelGGL(yolo_reduce_kernel, dim3(1), dim3(256), 0, stream,
                           part, out, NBLK);
        if (out_size > 4) {
            hipMemsetAsync(out + 4, 0, (size_t)(out_size - 4) * sizeof(float), stream);
        }
    } else {
        // fallback: contended-atomic path (d_out poisoned -> zero first)
        hipMemsetAsync(d_out, 0, (size_t)out_size * sizeof(float), stream);
        hipLaunchKernelGGL(yolo_loss_kernel, dim3(NBLK), dim3(TPB), 0, stream,
                           preds, targ, (float*)nullptr, out, n_cells, 1);
    }
}